// Round 1
// baseline (892.799 us; speedup 1.0000x reference)
//
#include <hip/hip_runtime.h>

#define MD 7
#define SD 10

// ---------------------------------------------------------------------------
// matched-dtype detector: jnp bool arrays are 1 byte/elem, but if the harness
// widens to int32, bytes at (i % 4 != 0) are all zero. Random 0/1 bools make
// P(first 1024 bytes fool us) ~ 2^-256. Writes 1 = uint8 layout, 0 = int32.
// ---------------------------------------------------------------------------
__global__ void detect_kernel(const unsigned char* __restrict__ mbytes,
                              int nbytes, int* __restrict__ flag)
{
    if (blockIdx.x == 0 && threadIdx.x == 0) {
        int f = 0;
        for (int i = 0; i < nbytes; i++) {
            if ((i & 3) != 0 && mbytes[i] != 0) { f = 1; break; }
        }
        *flag = f;
    }
}

__device__ __forceinline__ bool get_matched(const void* mptr, int n, int flag)
{
    if (flag) return ((const unsigned char*)mptr)[n] != 0;
    return ((const int*)mptr)[n] != 0;
}

// fps arrives as a 1-elem array; tolerate int32 or float32 storage.
__device__ __forceinline__ float load_scalar_f(const int* p)
{
    int v = *p;
    if (v >= -1000000 && v <= 1000000) return (float)v;
    union { int i; float f; } u; u.i = v; return u.f;
}

// ---------------------------------------------------------------------------
// Kalman-filter update: one thread per track.
//   matched:   Cholesky 7x7 solve, mean/cov/boxes/vel update
//   unmatched: constant/pass-through outputs; prev_covs/means/etc NOT loaded
// ---------------------------------------------------------------------------
__global__ __launch_bounds__(256) void kf_kernel(
    const float* __restrict__ boxes,   // N,12
    const float* __restrict__ obs,     // N,7
    const float* __restrict__ pb7,     // N,7
    const float* __restrict__ pmean,   // N,10
    const float* __restrict__ pcov,    // N,10,10
    const float* __restrict__ pvel,    // N,7
    const int*   __restrict__ accf,    // N
    const int*   __restrict__ fgap,    // N
    const void*  __restrict__ matched, // N (bool or int)
    const int*   __restrict__ fps_p,   // 1
    const int*   __restrict__ mflag,   // 1 (in d_ws)
    float* __restrict__ oboxes,        // N,12
    float* __restrict__ omean,         // N,10
    float* __restrict__ ocov,          // N,100
    float* __restrict__ ovel,          // N,7
    float* __restrict__ oacc,          // N
    int N)
{
    int n = blockIdx.x * blockDim.x + threadIdx.x;
    if (n >= N) return;

    const int  flag = *mflag;
    const bool m    = get_matched(matched, n, flag);
    const float fps = load_scalar_f(fps_p);

    // always needed: boxes (pass-through cols 6,7 or full), obs (innov or mean_i)
    float bx[12];
    {
        const float4* bp = (const float4*)(boxes + (size_t)n * 12);
        float4 a = bp[0], b = bp[1], c = bp[2];
        bx[0]=a.x; bx[1]=a.y; bx[2]=a.z;  bx[3]=a.w;
        bx[4]=b.x; bx[5]=b.y; bx[6]=b.z;  bx[7]=b.w;
        bx[8]=c.x; bx[9]=c.y; bx[10]=c.z; bx[11]=c.w;
    }
    float ob[7];
#pragma unroll
    for (int j = 0; j < 7; j++) ob[j] = obs[(size_t)n * 7 + j];

    float nb[12], nmu[10], CV[100], nvel[7], nacc;

    if (m) {
        // ---- load cov (25 x float4, 16B-aligned since row = 400 B) ----
        const float4* cp = (const float4*)(pcov + (size_t)n * 100);
#pragma unroll
        for (int i = 0; i < 25; i++) {
            float4 v = cp[i];
            CV[4*i+0] = v.x; CV[4*i+1] = v.y; CV[4*i+2] = v.z; CV[4*i+3] = v.w;
        }
        float mu[10];
        {
            const float2* mp = (const float2*)(pmean + (size_t)n * 10);
#pragma unroll
            for (int i = 0; i < 5; i++) { float2 v = mp[i]; mu[2*i] = v.x; mu[2*i+1] = v.y; }
        }

        // ---- Cholesky: S = CV[:7,:7] + I = L L^T  (SPD by construction) ----
        float L[7][7];
#pragma unroll
        for (int k = 0; k < 7; k++) {
            float d = CV[k*10 + k] + 1.0f;
#pragma unroll
            for (int q = 0; q < k; q++) d -= L[k][q] * L[k][q];
            float dk = sqrtf(d);
            L[k][k] = dk;
            float inv = 1.0f / dk;
#pragma unroll
            for (int i = k + 1; i < 7; i++) {
                float s = CV[i*10 + k];
#pragma unroll
                for (int q = 0; q < k; q++) s -= L[i][q] * L[k][q];
                L[i][k] = s * inv;
            }
        }

        // ---- solve S X = PHt^T  (B[j][l] = CV[l*10+j]),  X is 7x10 ----
        float X[7][10];
#pragma unroll
        for (int j = 0; j < 7; j++) {                 // forward: L Y = B
            float rinv = 1.0f / L[j][j];
#pragma unroll
            for (int l = 0; l < 10; l++) {
                float s = CV[l*10 + j];
#pragma unroll
                for (int q = 0; q < j; q++) s -= L[j][q] * X[q][l];
                X[j][l] = s * rinv;
            }
        }
#pragma unroll
        for (int j = 6; j >= 0; j--) {                // back: L^T X = Y
            float rinv = 1.0f / L[j][j];
#pragma unroll
            for (int l = 0; l < 10; l++) {
                float s = X[j][l];
#pragma unroll
                for (int q = j + 1; q < 7; q++) s -= L[q][j] * X[q][l];
                X[j][l] = s * rinv;
            }
        }

        // ---- mean update: mean_u[l] = mu[l] + sum_j X[j][l]*innov[j] ----
        float innov[7];
#pragma unroll
        for (int j = 0; j < 7; j++) innov[j] = ob[j] - mu[j];
        float mu_u[10];
#pragma unroll
        for (int l = 0; l < 10; l++) {
            float s = mu[l];
#pragma unroll
            for (int j = 0; j < 7; j++) s += X[j][l] * innov[j];
            mu_u[l] = s;
        }

        // ---- cov update in place: cov_u = CV - PHt*X  (== CV - K S K^T) ----
#pragma unroll
        for (int l = 0; l < 10; l++) {
            float r[10];
#pragma unroll
            for (int c = 0; c < 10; c++) {
                float s = 0.0f;
#pragma unroll
                for (int j = 0; j < 7; j++) s += CV[l*10 + j] * X[j][c];
                r[c] = CV[l*10 + c] - s;
            }
#pragma unroll
            for (int c = 0; c < 10; c++) CV[l*10 + c] = r[c];
        }

        // ---- boxes update ----
        // b_upd = [mu_u[0:6], bx[6], bx[7], mu_u[6], mu_u[7:10]*fps]
        // (pred_loc - mean_u[:3])[r] == mu_u[7+r] since F adds vel to pos
        nb[0] = mu_u[0]; nb[1] = mu_u[1]; nb[2] = mu_u[2];
        nb[3] = mu_u[3]; nb[4] = mu_u[4]; nb[5] = mu_u[5];
        nb[6] = bx[6];   nb[7] = bx[7];   nb[8] = mu_u[6];
        nb[9]  = mu_u[7] * fps;
        nb[10] = mu_u[8] * fps;
        nb[11] = mu_u[9] * fps;

        // ---- velocities / acc ----
        float gap = (float)fgap[n];
        float acc = (float)accf[n];
#pragma unroll
        for (int j = 0; j < 7; j++) {
            float vobs = (mu_u[j] - pb7[(size_t)n*7 + j]) / gap;
            nvel[j] = (pvel[(size_t)n*7 + j] * acc + vobs) / (acc + 1.0f);
        }
        nacc = acc + 1.0f;
#pragma unroll
        for (int l = 0; l < 10; l++) nmu[l] = mu_u[l];
    } else {
        // unmatched: constant init / pass-through. No prev_* loads at all.
#pragma unroll
        for (int i = 0; i < 100; i++) CV[i] = 0.0f;
#pragma unroll
        for (int l = 0; l < 7; l++)  CV[l*11] = 10.0f;     // INIT_POS_VAR
#pragma unroll
        for (int l = 7; l < 10; l++) CV[l*11] = 10000.0f;  // INIT_VEL_VAR
#pragma unroll
        for (int j = 0; j < 7; j++) nmu[j] = ob[j];
        nmu[7] = nmu[8] = nmu[9] = 0.0f;
#pragma unroll
        for (int i = 0; i < 12; i++) nb[i] = bx[i];
#pragma unroll
        for (int j = 0; j < 7; j++) nvel[j] = 0.0f;
        nacc = 0.0f;
    }

    // ---- coalesced-ish vector stores ----
    {
        float4* op = (float4*)(oboxes + (size_t)n * 12);
        op[0] = make_float4(nb[0], nb[1], nb[2],  nb[3]);
        op[1] = make_float4(nb[4], nb[5], nb[6],  nb[7]);
        op[2] = make_float4(nb[8], nb[9], nb[10], nb[11]);
    }
    {
        float2* op = (float2*)(omean + (size_t)n * 10);
#pragma unroll
        for (int i = 0; i < 5; i++) op[i] = make_float2(nmu[2*i], nmu[2*i+1]);
    }
    {
        float4* op = (float4*)(ocov + (size_t)n * 100);
#pragma unroll
        for (int i = 0; i < 25; i++)
            op[i] = make_float4(CV[4*i], CV[4*i+1], CV[4*i+2], CV[4*i+3]);
    }
#pragma unroll
    for (int j = 0; j < 7; j++) ovel[(size_t)n*7 + j] = nvel[j];
    oacc[n] = nacc;
}

// ---------------------------------------------------------------------------
// Embedding EMA: one wave (64 lanes x float4) per 256-wide row -> the matched
// branch is wave-uniform, so unmatched rows skip the prev_embeddings fetch.
// ---------------------------------------------------------------------------
__global__ __launch_bounds__(256) void emb_kernel(
    const float* __restrict__ pemb,    // N,256
    const float* __restrict__ emb,     // N,256
    const void*  __restrict__ matched, // N
    const int*   __restrict__ mflag,   // 1
    float* __restrict__ oemb,          // N,256
    int N)
{
    int gid  = blockIdx.x * 256 + threadIdx.x;
    int row  = gid >> 6;            // 64 lanes == exactly one 256-float row
    if (row >= N) return;
    int lane = gid & 63;

    const bool m = get_matched(matched, row, *mflag);
    size_t idx = (size_t)row * 64 + lane;

    float4 e = ((const float4*)emb)[idx];
    float4 o;
    if (m) {
        float4 p = ((const float4*)pemb)[idx];
        o.x = 0.2f * p.x + 0.8f * e.x;
        o.y = 0.2f * p.y + 0.8f * e.y;
        o.z = 0.2f * p.z + 0.8f * e.z;
        o.w = 0.2f * p.w + 0.8f * e.w;
    } else {
        o = e;
    }
    ((float4*)oemb)[idx] = o;
}

extern "C" void kernel_launch(void* const* d_in, const int* in_sizes, int n_in,
                              void* d_out, int out_size, void* d_ws, size_t ws_size,
                              hipStream_t stream)
{
    const float* boxes  = (const float*)d_in[0];
    const float* obs    = (const float*)d_in[1];
    const float* pb7    = (const float*)d_in[2];
    const float* pmean  = (const float*)d_in[3];
    const float* pcov   = (const float*)d_in[4];
    const float* pvel   = (const float*)d_in[5];
    const float* pemb   = (const float*)d_in[6];
    const float* emb    = (const float*)d_in[7];
    const int*   accf   = (const int*)d_in[8];
    const int*   fgap   = (const int*)d_in[9];
    const void*  matched= d_in[10];
    const int*   fps_p  = (const int*)d_in[11];
    const int N = in_sizes[8];   // acc_frames element count == N tracks

    float* out = (float*)d_out;
    float* oboxes = out;
    float* omean  = out + (size_t)N * 12;
    float* ocov   = out + (size_t)N * 22;
    float* ovel   = out + (size_t)N * 122;
    float* oemb   = out + (size_t)N * 129;
    float* oacc   = out + (size_t)N * 385;

    int* mflag = (int*)d_ws;

    detect_kernel<<<1, 64, 0, stream>>>((const unsigned char*)matched, 1024, mflag);
    kf_kernel<<<(N + 255) / 256, 256, 0, stream>>>(
        boxes, obs, pb7, pmean, pcov, pvel, accf, fgap, matched, fps_p, mflag,
        oboxes, omean, ocov, ovel, oacc, N);
    emb_kernel<<<N / 4, 256, 0, stream>>>(pemb, emb, matched, mflag, oemb, N);
}

// Round 2
// 852.821 us; speedup vs baseline: 1.0469x; 1.0469x over previous
//
#include <hip/hip_runtime.h>

// ---------------------------------------------------------------------------
// matched-dtype detector (parallel, one wave): jnp bool arrays are 1 B/elem;
// if the harness widens to int32, all bytes at (i % 4 != 0) are zero. With
// ~768 random 0/1 payload bytes inspected, misdetection P ~ 2^-768.
// flag = 1 -> uint8 layout, 0 -> int32 layout.
// ---------------------------------------------------------------------------
__global__ void detect_kernel(const unsigned char* __restrict__ mbytes,
                              int nbytes, int* __restrict__ flag)
{
    int t = threadIdx.x;              // 64 threads = one wave
    int f = 0;
    for (int i = t; i < nbytes; i += 64)
        if ((i & 3) != 0 && mbytes[i] != 0) f = 1;
    unsigned long long b = __ballot(f != 0);
    if (t == 0) *flag = (b != 0ULL) ? 1 : 0;
}

__device__ __forceinline__ bool get_matched(const void* mptr, int n, int flag)
{
    if (flag) return ((const unsigned char*)mptr)[n] != 0;
    return ((const int*)mptr)[n] != 0;
}

// fps arrives as a 1-elem array; tolerate int32 or float32 storage.
__device__ __forceinline__ float load_scalar_f(const int* p)
{
    int v = *p;
    if (v >= -1000000 && v <= 1000000) return (float)v;
    union { int i; float f; } u; u.i = v; return u.f;
}

// ---------------------------------------------------------------------------
// Kalman-filter update: one thread per track. Register-lean formulation:
// prev_covs is symmetric (A A^T + I), so the solve + cov update only need
//   W[l][j] = cov[l][j]  (10x7 block, j<7)         -> PHt AND S AND rhs
//   V3      = cov[7:,7:] (3x3 velocity block)
// cov[l][c] for c>=7, l<7 is W[c][l] by symmetry. Peak live ~200 VGPRs,
// no spills at __launch_bounds__(256,2).
// ---------------------------------------------------------------------------
__global__ __launch_bounds__(256, 2) void kf_kernel(
    const float* __restrict__ boxes,   // N,12
    const float* __restrict__ obs,     // N,7
    const float* __restrict__ pb7,     // N,7
    const float* __restrict__ pmean,   // N,10
    const float* __restrict__ pcov,    // N,10,10
    const float* __restrict__ pvel,    // N,7
    const int*   __restrict__ accf,    // N
    const int*   __restrict__ fgap,    // N
    const void*  __restrict__ matched, // N (bool or int)
    const int*   __restrict__ fps_p,   // 1
    const int*   __restrict__ mflag,   // 1 (in d_ws)
    float* __restrict__ oboxes,        // N,12
    float* __restrict__ omean,         // N,10
    float* __restrict__ ocov,          // N,100
    float* __restrict__ ovel,          // N,7
    float* __restrict__ oacc,          // N
    int N)
{
    int n = blockIdx.x * blockDim.x + threadIdx.x;
    if (n >= N) return;

    const int  flag = *mflag;
    const bool m    = get_matched(matched, n, flag);

    // obs needed in both paths (innov / mean_i)
    float ob[7];
#pragma unroll
    for (int j = 0; j < 7; j++) ob[j] = obs[(size_t)n * 7 + j];

    if (m) {
        const float fps = load_scalar_f(fps_p);

        // ---- load cov, keep only unique content: W (10x7) + V3 (3x3) ----
        float W[10][7], V3[3][3];
        {
            const float4* cp = (const float4*)(pcov + (size_t)n * 100);
#pragma unroll
            for (int i = 0; i < 25; i++) {
                float4 v = cp[i];
                float vv[4] = {v.x, v.y, v.z, v.w};
#pragma unroll
                for (int k = 0; k < 4; k++) {
                    const int e = 4 * i + k, l = e / 10, c = e % 10;
                    if (c < 7)            W[l][c]        = vv[k];
                    else if (l >= 7)      V3[l-7][c-7]   = vv[k];
                    // (l<7, c>=7): discarded, recovered via symmetry
                }
            }
        }
        float mu[10];
        {
            const float2* mp = (const float2*)(pmean + (size_t)n * 10);
#pragma unroll
            for (int i = 0; i < 5; i++) { float2 v = mp[i]; mu[2*i] = v.x; mu[2*i+1] = v.y; }
        }

        // ---- Cholesky: S = W[:7,:7] + I = L L^T (SPD by construction) ----
        float L[7][7];
#pragma unroll
        for (int k = 0; k < 7; k++) {
            float d = W[k][k] + 1.0f;
#pragma unroll
            for (int q = 0; q < k; q++) d -= L[k][q] * L[k][q];
            float dk = sqrtf(d);
            L[k][k] = dk;
            float inv = 1.0f / dk;
#pragma unroll
            for (int i = k + 1; i < 7; i++) {
                float s = W[i][k];
#pragma unroll
                for (int q = 0; q < k; q++) s -= L[i][q] * L[k][q];
                L[i][k] = s * inv;
            }
        }

        // ---- solve S X = PHt^T; rhs B[j][l] = cov[l][j] = W[l][j] ----
        float X[7][10];
#pragma unroll
        for (int j = 0; j < 7; j++) {                 // forward: L Y = B
            float rinv = 1.0f / L[j][j];
#pragma unroll
            for (int l = 0; l < 10; l++) {
                float s = W[l][j];
#pragma unroll
                for (int q = 0; q < j; q++) s -= L[j][q] * X[q][l];
                X[j][l] = s * rinv;
            }
        }
#pragma unroll
        for (int j = 6; j >= 0; j--) {                // back: L^T X = Y
            float rinv = 1.0f / L[j][j];
#pragma unroll
            for (int l = 0; l < 10; l++) {
                float s = X[j][l];
#pragma unroll
                for (int q = j + 1; q < 7; q++) s -= L[q][j] * X[q][l];
                X[j][l] = s * rinv;
            }
        }
        // L dead from here.

        // ---- mean update ----
        float innov[7];
#pragma unroll
        for (int j = 0; j < 7; j++) innov[j] = ob[j] - mu[j];
        float mu_u[10];
#pragma unroll
        for (int l = 0; l < 10; l++) {
            float s = mu[l];
#pragma unroll
            for (int j = 0; j < 7; j++) s += X[j][l] * innov[j];
            mu_u[l] = s;
        }
        // mu, ob, innov dead from here.

        // ---- cov_u = cov - PHt*X, streamed out float4 at a time ----
        {
            float4* op = (float4*)(ocov + (size_t)n * 100);
#pragma unroll
            for (int i = 0; i < 25; i++) {
                float r[4];
#pragma unroll
                for (int k = 0; k < 4; k++) {
                    const int e = 4 * i + k, l = e / 10, c = e % 10;
                    float base = (c < 7) ? W[l][c]
                               : ((l < 7) ? W[c][l] : V3[l-7][c-7]);
                    float s = 0.0f;
#pragma unroll
                    for (int j = 0; j < 7; j++) s += W[l][j] * X[j][c];
                    r[k] = base - s;
                }
                op[i] = make_float4(r[0], r[1], r[2], r[3]);
            }
        }
        // W, V3, X dead from here.

        // ---- boxes: [mu_u[0:6], bx6, bx7, mu_u[6], mu_u[7:10]*fps] ----
        // (pred_loc - mean_u[:3])[r] == mu_u[7+r] since F adds vel to pos.
        float bx6, bx7;
        {
            const float4* bp = (const float4*)(boxes + (size_t)n * 12);
            float4 b = bp[1];            // elements 4..7
            bx6 = b.z; bx7 = b.w;
        }
        {
            float4* op = (float4*)(oboxes + (size_t)n * 12);
            op[0] = make_float4(mu_u[0], mu_u[1], mu_u[2], mu_u[3]);
            op[1] = make_float4(mu_u[4], mu_u[5], bx6,     bx7);
            op[2] = make_float4(mu_u[6], mu_u[7] * fps, mu_u[8] * fps, mu_u[9] * fps);
        }
        {
            float2* op = (float2*)(omean + (size_t)n * 10);
#pragma unroll
            for (int i = 0; i < 5; i++) op[i] = make_float2(mu_u[2*i], mu_u[2*i+1]);
        }

        // ---- velocities / acc ----
        float gap  = (float)fgap[n];
        float acc  = (float)accf[n];
        float ginv = 1.0f / gap;
        float ainv = 1.0f / (acc + 1.0f);
#pragma unroll
        for (int j = 0; j < 7; j++) {
            float vobs = (mu_u[j] - pb7[(size_t)n*7 + j]) * ginv;
            ovel[(size_t)n*7 + j] = (pvel[(size_t)n*7 + j] * acc + vobs) * ainv;
        }
        oacc[n] = acc + 1.0f;
    } else {
        // unmatched: constant init / pass-through; no prev_* loads at all.
        {
            const float4* bp = (const float4*)(boxes + (size_t)n * 12);
            float4* op = (float4*)(oboxes + (size_t)n * 12);
            op[0] = bp[0]; op[1] = bp[1]; op[2] = bp[2];
        }
        {
            float2* op = (float2*)(omean + (size_t)n * 10);
            op[0] = make_float2(ob[0], ob[1]);
            op[1] = make_float2(ob[2], ob[3]);
            op[2] = make_float2(ob[4], ob[5]);
            op[3] = make_float2(ob[6], 0.0f);
            op[4] = make_float2(0.0f, 0.0f);
        }
        {
            float4* op = (float4*)(ocov + (size_t)n * 100);
#pragma unroll
            for (int i = 0; i < 25; i++) {
                float r[4];
#pragma unroll
                for (int k = 0; k < 4; k++) {
                    const int e = 4 * i + k, l = e / 10, c = e % 10;
                    r[k] = (l == c) ? ((l < 7) ? 10.0f : 10000.0f) : 0.0f;
                }
                op[i] = make_float4(r[0], r[1], r[2], r[3]);
            }
        }
#pragma unroll
        for (int j = 0; j < 7; j++) ovel[(size_t)n*7 + j] = 0.0f;
        oacc[n] = 0.0f;
    }
}

// ---------------------------------------------------------------------------
// Embedding EMA: one wave (64 lanes x float4) per 256-wide row -> the matched
// branch is wave-uniform, so unmatched rows skip the prev_embeddings fetch.
// ---------------------------------------------------------------------------
__global__ __launch_bounds__(256) void emb_kernel(
    const float* __restrict__ pemb,    // N,256
    const float* __restrict__ emb,     // N,256
    const void*  __restrict__ matched, // N
    const int*   __restrict__ mflag,   // 1
    float* __restrict__ oemb,          // N,256
    int N)
{
    int gid  = blockIdx.x * 256 + threadIdx.x;
    int row  = gid >> 6;            // 64 lanes == exactly one 256-float row
    if (row >= N) return;
    int lane = gid & 63;

    const bool m = get_matched(matched, row, *mflag);
    size_t idx = (size_t)row * 64 + lane;

    float4 e = ((const float4*)emb)[idx];
    float4 o;
    if (m) {
        float4 p = ((const float4*)pemb)[idx];
        o.x = 0.2f * p.x + 0.8f * e.x;
        o.y = 0.2f * p.y + 0.8f * e.y;
        o.z = 0.2f * p.z + 0.8f * e.z;
        o.w = 0.2f * p.w + 0.8f * e.w;
    } else {
        o = e;
    }
    ((float4*)oemb)[idx] = o;
}

extern "C" void kernel_launch(void* const* d_in, const int* in_sizes, int n_in,
                              void* d_out, int out_size, void* d_ws, size_t ws_size,
                              hipStream_t stream)
{
    const float* boxes  = (const float*)d_in[0];
    const float* obs    = (const float*)d_in[1];
    const float* pb7    = (const float*)d_in[2];
    const float* pmean  = (const float*)d_in[3];
    const float* pcov   = (const float*)d_in[4];
    const float* pvel   = (const float*)d_in[5];
    const float* pemb   = (const float*)d_in[6];
    const float* emb    = (const float*)d_in[7];
    const int*   accf   = (const int*)d_in[8];
    const int*   fgap   = (const int*)d_in[9];
    const void*  matched= d_in[10];
    const int*   fps_p  = (const int*)d_in[11];
    const int N = in_sizes[8];   // acc_frames element count == N tracks

    float* out = (float*)d_out;
    float* oboxes = out;
    float* omean  = out + (size_t)N * 12;
    float* ocov   = out + (size_t)N * 22;
    float* ovel   = out + (size_t)N * 122;
    float* oemb   = out + (size_t)N * 129;
    float* oacc   = out + (size_t)N * 385;

    int* mflag = (int*)d_ws;

    detect_kernel<<<1, 64, 0, stream>>>((const unsigned char*)matched, 1024, mflag);
    kf_kernel<<<(N + 255) / 256, 256, 0, stream>>>(
        boxes, obs, pb7, pmean, pcov, pvel, accf, fgap, matched, fps_p, mflag,
        oboxes, omean, ocov, ovel, oacc, N);
    emb_kernel<<<(N + 3) / 4, 256, 0, stream>>>(pemb, emb, matched, mflag, oemb, N);
}